// Round 6
// baseline (123.209 us; speedup 1.0000x reference)
//
#include <hip/hip_runtime.h>
#include <math.h>

// CepstrumToImpulseResponse: h[0]=exp(c[0]); h[n] = (1/n) * sum_{m=1}^{min(n,99)} m*c[m]*h[n-m]
// B=65536, M=99, N=512. Output float32 [B, 512].
//
// Round-6: 4 lanes per batch row (one quad). Lane l owns taps m = 25l+1 .. 25l+25
// (lane 3's m=100 tap zeroed). Persistent per-lane state: w[25] + hh[41] -- small
// enough to live entirely in arch VGPRs (rounds 3-5 were stuck at VGPR_Count=88
// with ~130-float live sets -> AGPR shuttling, ~2x VALU-instruction inflation).
// Occupancy 2 -> 4 waves/SIMD.
//
// Frames (all-static indexing): lane l: hh[i] = h(n0 + 15 - 25l - i), i=0..40.
//   Step j (n_j = n0+j) : partial = sum_k w[k]*hh[k+16-j]  (k+16-j in [1,40]).
//   Quad reduce: xor1 + xor2 DPP butterflies -> all 4 lanes hold hn.
//   Fresh h(n0+j) -> slot 15-j, lane 0 (base) only.
//   Group end: bv[jj] = row_shr1(hh[9+jj]) pulls from lane l-1 (base lanes get
//   dead data); shift hh[40..16] <- hh[24..0]; hh[0..15] <- bv.
// Output staged in LDS (64 rows x stride 129, dump col 128) and flushed
// coalesced every 128 columns.

#define NROWS   64    // rows per 256-thread block (4 lanes per row)
#define STRIDE  129   // LDS row stride in floats; col 128 = dump slot

__device__ __forceinline__ float dpp_xor1(float x) {   // quad_perm [1,0,3,2]
    return __int_as_float(__builtin_amdgcn_mov_dpp(__float_as_int(x), 0xB1, 0xF, 0xF, false));
}
__device__ __forceinline__ float dpp_xor2(float x) {   // quad_perm [2,3,0,1]
    return __int_as_float(__builtin_amdgcn_mov_dpp(__float_as_int(x), 0x4E, 0xF, 0xF, false));
}
__device__ __forceinline__ float dpp_shr1(float x) {   // row_shr:1 (lane l <- l-1)
    return __int_as_float(__builtin_amdgcn_mov_dpp(__float_as_int(x), 0x111, 0xF, 0xF, false));
}

__global__ __launch_bounds__(256, 4)
void cep2ir_kernel(const float* __restrict__ c, float* __restrict__ out) {
    __shared__ float stage[NROWS * STRIDE];
    const int t = threadIdx.x;
    const int l = t & 3;                     // lane within quad: tap-block owner
    const int lrow = t >> 2;                 // local row 0..63
    const bool isBase = (l == 0);
    const int rowbase = blockIdx.x * NROWS;
    const float* cb = c + (size_t)(rowbase + lrow) * 100;
    float* outb = out + (size_t)rowbase * 512;

    // Load 7 float4 starting at block b0 = {0,6,12,19}[l]; lane 3's 7th block
    // clamped to 24 (row has exactly 25 float4). e[] covers c[base..base+27].
    float e[28];
    {
        const float4* c4 = reinterpret_cast<const float4*>(cb);
        const int b0 = 6 * l + (l == 3 ? 1 : 0);
#pragma unroll
        for (int i = 0; i < 7; ++i) {
            int blk = b0 + i;
            if (l == 3 && i == 6) blk = 24;
            const float4 v = c4[blk];
            e[4 * i + 0] = v.x; e[4 * i + 1] = v.y;
            e[4 * i + 2] = v.z; e[4 * i + 3] = v.w;
        }
    }
    // w[k] = c[25l+k+1] * (25l+k+1). Offset of c[25l+1] in e[]: {1,2,3,0}[l].
    float w[25];
    {
        const float lf = (float)l;
#pragma unroll
        for (int k = 0; k < 25; ++k) {
            const float ce = (l == 0) ? e[k + 1] : (l == 1) ? e[k + 2]
                           : (l == 2) ? e[k + 3] : e[k];
            w[k] = ce * (25.0f * lf + (float)(k + 1));
        }
        if (l == 3) w[24] = 0.0f;   // m=100 doesn't exist
    }

    const float h0 = expf(e[0]);  // meaningful on base lanes only

    float hh[41];
#pragma unroll
    for (int k = 0; k < 41; ++k) hh[k] = 0.0f;
    hh[16] = isBase ? h0 : 0.0f;

    if (isBase) stage[lrow * STRIDE] = h0;   // col 0 of phase 0

    float fn = 1.0f;    // n at j=0 of current group
    float carry = 0.0f; // h(128*(p+1)) -> col 0 of next phase

#pragma unroll 1
    for (int p = 0; p < 4; ++p) {
        float* sp = &stage[lrow * STRIDE + 1];
#pragma unroll 1
        for (int gg = 0; gg < 8; ++gg) {
            float rn[16];
#pragma unroll
            for (int j = 0; j < 16; ++j) rn[j] = __builtin_amdgcn_rcpf(fn + (float)j);

#pragma unroll
            for (int j = 0; j < 16; ++j) {
                float a0 = 0.f, a1 = 0.f;
#pragma unroll
                for (int k = 0; k < 25; ++k) {
                    if ((k & 1) == 0) a0 = __builtin_fmaf(w[k], hh[k + 16 - j], a0);
                    else              a1 = __builtin_fmaf(w[k], hh[k + 16 - j], a1);
                }
                float s = a0 + a1;
                s += dpp_xor1(s);
                s += dpp_xor2(s);            // all 4 lanes now hold the full sum
                const float hn = s * rn[j];
                hh[15 - j] = isBase ? hn : hh[15 - j];
                if (j == 15) carry = hn;
            }
            // Batched output stores: lane 0's hh[15..0] = h(n0 .. n0+15).
            if (isBase) {
#pragma unroll
                for (int j = 0; j < 16; ++j) sp[j] = hh[15 - j];  // last lands in dump col
            }
            // Boundary: lane l receives lane (l-1)'s hh[9..24] as its next slots 0..15.
            float bv[16];
#pragma unroll
            for (int jj = 0; jj < 16; ++jj) bv[jj] = dpp_shr1(hh[9 + jj]);
#pragma unroll
            for (int k = 40; k >= 16; --k) hh[k] = hh[k - 16];
#pragma unroll
            for (int jj = 0; jj < 16; ++jj) hh[jj] = bv[jj];  // base lanes: dead slots
            fn += 16.0f;
            sp += 16;
        }
        __syncthreads();
        // Coalesced flush: 64 rows x 128 cols -> out[row][128p .. 128p+127].
#pragma unroll 1
        for (int i = 0; i < 32; ++i) {
            const int idx = i * 256 + t;
            const int r = idx >> 7;
            const int cc = idx & 127;
            outb[(size_t)r * 512 + p * 128 + cc] = stage[r * STRIDE + cc];
        }
        __syncthreads();
        if (p < 3 && isBase) stage[lrow * STRIDE] = carry;  // col 0 of next phase
    }
}

extern "C" void kernel_launch(void* const* d_in, const int* in_sizes, int n_in,
                              void* d_out, int out_size, void* d_ws, size_t ws_size,
                              hipStream_t stream) {
    const float* c = (const float*)d_in[0];
    float* out = (float*)d_out;
    // 4 lanes per row: 65536 rows * 4 / 256 = 1024 blocks (4 per CU).
    cep2ir_kernel<<<1024, 256, 0, stream>>>(c, out);
}

// Round 7
// 118.266 us; speedup vs baseline: 1.0418x; 1.0418x over previous
//
#include <hip/hip_runtime.h>
#include <math.h>

// CepstrumToImpulseResponse: h[0]=exp(c[0]); h[n] = (1/n) sum_{m=1..99} m*c[m]*h[n-m]
// B=65536, M=99, N=512. Output float32 [B, 512].
//
// Round-7: packed fp32. Each thread owns TWO batch rows (float2 components) and a
// 25-tap block (4-lane quad split, lane l: taps m=25l+1..25l+25; lane3 m=100 pad=0).
// Inner product = 25 x v_pk_fma_f32 (inline asm; VOP3P, gfx90a+). Index math is
// round-6's verified mapping, lifted to float2:
//   lane l frame: hh2[i] = h(n0+15-25l-i), i=0..40 (per row component).
//   step j: acc += w2[k]*hh2[k+16-j]; quad reduce via DPP xor1+xor2 per component;
//   fresh h -> slot 15-j on base lane; group end: bv2[jj]=row_shr1(hh2[9+jj]),
//   shift by 16, bv into slots 0..15.
// Output staged in LDS (128 rows x stride 129, col 128 = dump) -> coalesced flush.

#define NROWS   128   // local rows per block (64 quads x 2 rows)
#define STRIDE  129

typedef float f2 __attribute__((ext_vector_type(2)));

__device__ __forceinline__ float dpp_xor1(float x) {   // quad_perm [1,0,3,2]
    return __int_as_float(__builtin_amdgcn_mov_dpp(__float_as_int(x), 0xB1, 0xF, 0xF, false));
}
__device__ __forceinline__ float dpp_xor2(float x) {   // quad_perm [2,3,0,1]
    return __int_as_float(__builtin_amdgcn_mov_dpp(__float_as_int(x), 0x4E, 0xF, 0xF, false));
}
__device__ __forceinline__ float dpp_shr1(float x) {   // row_shr:1
    return __int_as_float(__builtin_amdgcn_mov_dpp(__float_as_int(x), 0x111, 0xF, 0xF, false));
}
__device__ __forceinline__ f2 pk_fma(f2 a, f2 b, f2 c) {
    f2 d;
    asm("v_pk_fma_f32 %0, %1, %2, %3" : "=v"(d) : "v"(a), "v"(b), "v"(c));
    return d;
}

__global__ __launch_bounds__(256, 2)
void cep2ir_kernel(const float* __restrict__ c, float* __restrict__ out) {
    __shared__ float stage[NROWS * STRIDE];
    const int t = threadIdx.x;
    const int l = t & 3;                 // tap-block owner within quad
    const int q = t >> 2;                // quad id = local row-pair 0..63
    const bool isBase = (l == 0);
    const int r0 = 2 * q;                // local rows r0, r0+1
    const int rowbase = blockIdx.x * NROWS;
    float* outb = out + (size_t)rowbase * 512;

    // Weights for both rows: w2[k] = c[25l+k+1]*(25l+k+1) (x: row r0, y: row r0+1).
    f2 w2[25];
    f2 h02;
    {
#pragma unroll
        for (int r = 0; r < 2; ++r) {
            const float* cb = c + (size_t)(rowbase + r0 + r) * 100;
            const float4* c4 = reinterpret_cast<const float4*>(cb);
            float e[28];
            const int b0 = 6 * l + (l == 3 ? 1 : 0);
#pragma unroll
            for (int i = 0; i < 7; ++i) {
                int blk = b0 + i;
                if (l == 3 && i == 6) blk = 24;
                const float4 v = c4[blk];
                e[4 * i + 0] = v.x; e[4 * i + 1] = v.y;
                e[4 * i + 2] = v.z; e[4 * i + 3] = v.w;
            }
            const float lf = (float)l;
#pragma unroll
            for (int k = 0; k < 25; ++k) {
                const float ce = (l == 0) ? e[k + 1] : (l == 1) ? e[k + 2]
                               : (l == 2) ? e[k + 3] : e[k];
                const float wk = ce * (25.0f * lf + (float)(k + 1));
                if (r == 0) w2[k].x = wk; else w2[k].y = wk;
            }
            const float h0 = expf(e[0]);
            if (r == 0) h02.x = h0; else h02.y = h0;
        }
        if (l == 3) { w2[24].x = 0.0f; w2[24].y = 0.0f; }  // m=100 pad
    }

    f2 hh2[41];
#pragma unroll
    for (int k = 0; k < 41; ++k) { hh2[k].x = 0.0f; hh2[k].y = 0.0f; }
    if (isBase) hh2[16] = h02;

    float* sp0 = &stage[r0 * STRIDE];        // row r0; row r0+1 = sp0 + STRIDE
    if (isBase) { sp0[0] = h02.x; sp0[STRIDE] = h02.y; }  // col 0 of phase 0

    float fn = 1.0f;
    f2 carry; carry.x = 0.0f; carry.y = 0.0f;

#pragma unroll 1
    for (int p = 0; p < 4; ++p) {
#pragma unroll 1
        for (int gg = 0; gg < 8; ++gg) {
            float rn[16];
#pragma unroll
            for (int j = 0; j < 16; ++j) rn[j] = __builtin_amdgcn_rcpf(fn + (float)j);

#pragma unroll
            for (int j = 0; j < 16; ++j) {
                f2 a0, a1;
                a0.x = 0.f; a0.y = 0.f; a1.x = 0.f; a1.y = 0.f;
#pragma unroll
                for (int k = 0; k < 25; ++k) {
                    if ((k & 1) == 0) a0 = pk_fma(w2[k], hh2[k + 16 - j], a0);
                    else              a1 = pk_fma(w2[k], hh2[k + 16 - j], a1);
                }
                f2 s = a0 + a1;
                f2 tt;
                tt.x = dpp_xor1(s.x); tt.y = dpp_xor1(s.y); s += tt;
                tt.x = dpp_xor2(s.x); tt.y = dpp_xor2(s.y); s += tt;
                f2 hn;
                hn.x = s.x * rn[j]; hn.y = s.y * rn[j];
                hh2[15 - j].x = isBase ? hn.x : hh2[15 - j].x;
                hh2[15 - j].y = isBase ? hn.y : hh2[15 - j].y;
                if (j == 15) carry = hn;
            }
            // Batched stores: base lane's hh2[15..0] = h(n0..n0+15), both rows.
            // Column base within phase: 1 + 16*gg; gg=7,j=15 lands in dump col 128.
            if (isBase) {
                float* sc = sp0 + 1 + 16 * gg;
#pragma unroll
                for (int j = 0; j < 16; ++j) {
                    sc[j] = hh2[15 - j].x;
                    sc[STRIDE + j] = hh2[15 - j].y;
                }
            }
            // Boundary: lane l pulls lane (l-1)'s hh2[9..24] (base lanes: dead data).
            f2 bv[16];
#pragma unroll
            for (int jj = 0; jj < 16; ++jj) {
                bv[jj].x = dpp_shr1(hh2[9 + jj].x);
                bv[jj].y = dpp_shr1(hh2[9 + jj].y);
            }
#pragma unroll
            for (int k = 40; k >= 16; --k) hh2[k] = hh2[k - 16];
#pragma unroll
            for (int jj = 0; jj < 16; ++jj) hh2[jj] = bv[jj];
            fn += 16.0f;
        }
        __syncthreads();
        // Coalesced flush: 128 rows x 128 cols -> out[row][128p .. 128p+127].
#pragma unroll 1
        for (int i = 0; i < 64; ++i) {
            const int idx = i * 256 + t;
            const int r = idx >> 7;
            const int cc = idx & 127;
            outb[(size_t)r * 512 + p * 128 + cc] = stage[r * STRIDE + cc];
        }
        __syncthreads();
        if (p < 3 && isBase) { sp0[0] = carry.x; sp0[STRIDE] = carry.y; }
    }
}

extern "C" void kernel_launch(void* const* d_in, const int* in_sizes, int n_in,
                              void* d_out, int out_size, void* d_ws, size_t ws_size,
                              hipStream_t stream) {
    const float* c = (const float*)d_in[0];
    float* out = (float*)d_out;
    // 2 rows/thread, 4 lanes/row-pair: 65536/128 = 512 blocks of 256.
    cep2ir_kernel<<<512, 256, 0, stream>>>(c, out);
}

// Round 8
// 104.282 us; speedup vs baseline: 1.1815x; 1.1341x over previous
//
#include <hip/hip_runtime.h>
#include <math.h>

// CepstrumToImpulseResponse: h[0]=exp(c[0]); h[n] = (1/n) sum_{m=1..99} m*c[m]*h[n-m]
// B=65536, M=99, N=512. Output float32 [B, 512].
//
// Structure (best = round 5, refined): 2 lanes per batch row (A: taps m=1..50,
// B: m=51..99), uniform 82-slot register window, all-static indexing, U=32 time
// unroll, DPP xor-1 pair reduce, LDS-staged coalesced output flush.
//
// Round-8: (a) U=16 -> 32: shift movs 3.1 -> 1.6/step. (b) 1/n from a 511-entry
// LDS table (built once; 8x ds_read_b128/group, broadcast) instead of 32 rcp+add
// per group. (c) output stores batched at group end (one exec-masked run of 32).
// Static FMA density ~78% -> ~86%. Pure-FMA floor at the m07-measured 103 TF
// sustained fp32 rate is ~64 us.
//
// Index map (U=32, re-derived): frame A: hh[i]=h(n0+31-i); B: hh[i]=h(n0-19-i).
//   step j, tap k: read s = k+32-j (in [1,81]); fresh h(n0+j) -> slot 31-j (A only).
//   group end: bv[i] = xor1(hh[18+i]) (i=0..31, read pre-shift); shift
//   hh[81..32] <- hh[49..0]; hh[0..31] <- bv. Seed h(0) at slot 32 (n0=1).
//   Phase carry: post-shift hh[32] = h(128(p+1)).

#define NROWS   128   // rows per 256-thread block (2 lanes per row)
#define STRIDE  129   // LDS row stride in floats; col 128 = dump slot

__device__ __forceinline__ float dpp_xor1(float x) {   // quad_perm [1,0,3,2]
    return __int_as_float(__builtin_amdgcn_mov_dpp(__float_as_int(x), 0xB1, 0xF, 0xF, false));
}

__global__ __launch_bounds__(256, 2)
void cep2ir_kernel(const float* __restrict__ c, float* __restrict__ out) {
    __shared__ float stage[NROWS * STRIDE];
    __shared__ float4 rn4[128];              // ((float*)rn4)[i] = 1/(i+1), i=0..510
    const int t = threadIdx.x;
    const int lrow = t >> 1;                 // local row 0..127
    const bool isA = (t & 1) == 0;
    const int rowbase = blockIdx.x * NROWS;
    const float* cb = c + (size_t)(rowbase + lrow) * 100;
    float* outb = out + (size_t)rowbase * 512;

    // 1/n table: each thread fills entries t and t+256.
    {
        float* rt = reinterpret_cast<float*>(rn4);
        rt[t]       = __builtin_amdgcn_rcpf((float)(t + 1));
        rt[t + 256] = __builtin_amdgcn_rcpf((float)(t + 257));
    }

    // Load 13 float4 = 52 floats: A covers c[0..51], B covers c[48..99].
    float e[52];
    {
        const float4* c4 = reinterpret_cast<const float4*>(cb);
        const int f4b = isA ? 0 : 12;
#pragma unroll
        for (int i = 0; i < 13; ++i) {
            const float4 v = c4[f4b + i];
            e[4 * i + 0] = v.x; e[4 * i + 1] = v.y;
            e[4 * i + 2] = v.z; e[4 * i + 3] = v.w;
        }
    }
    // Weights: A: w[k]=c[k+1]*(k+1); B: w[k]=c[51+k]*(51+k), k=0..48; w[49]=0 on B.
    float w[50];
#pragma unroll
    for (int k = 0; k < 49; ++k)
        w[k] = (isA ? e[k + 1] : e[k + 3]) * (isA ? (float)(k + 1) : (float)(k + 51));
    w[49] = isA ? e[50] * 50.0f : 0.0f;

    const float h0 = expf(e[0]);  // meaningful on lane A

    float hh[82];
#pragma unroll
    for (int k = 0; k < 82; ++k) hh[k] = 0.0f;
    hh[32] = isA ? h0 : 0.0f;     // h(0) in A frame (n0=1)

    if (isA) stage[lrow * STRIDE] = h0;   // col 0 of phase 0
    __syncthreads();                      // rn table + h0 staged

#pragma unroll 1
    for (int p = 0; p < 4; ++p) {
#pragma unroll 1
        for (int gg = 0; gg < 4; ++gg) {
            // 1/n for the 32 steps: broadcast ds_read_b128 x8, off the chain.
            float4 r4[8];
            {
                const float4* rp = &rn4[8 * (4 * p + gg)];
#pragma unroll
                for (int i = 0; i < 8; ++i) r4[i] = rp[i];
            }
#pragma unroll
            for (int j = 0; j < 32; ++j) {
                float a0 = 0.f, a1 = 0.f;
#pragma unroll
                for (int k = 0; k < 50; ++k) {
                    if ((k & 1) == 0) a0 = __builtin_fmaf(w[k], hh[k + 32 - j], a0);
                    else              a1 = __builtin_fmaf(w[k], hh[k + 32 - j], a1);
                }
                float s = a0 + a1;
                s += dpp_xor1(s);                       // pair reduce (fusable DPP)
                const float rn = (j & 2) ? ((j & 1) ? r4[j >> 2].w : r4[j >> 2].z)
                                         : ((j & 1) ? r4[j >> 2].y : r4[j >> 2].x);
                const float hn = s * rn;
                hh[31 - j] = isA ? hn : hh[31 - j];     // only A's frame takes fresh h
            }
            // Batched stores: A's hh[31..0] = h(n0..n0+31) -> cols 1+32gg .. 32+32gg.
            // (gg==3, j==31 lands in dump col 128; n=128(p+1) re-emerges as carry.)
            if (isA) {
                float* sc = &stage[lrow * STRIDE + 1 + 32 * gg];
#pragma unroll
                for (int j = 0; j < 32; ++j) sc[j] = hh[31 - j];
            }
            // Boundary (pre-shift reads): B's next slots 0..31 = A's h(n0+13..n0-18).
            float bv[32];
#pragma unroll
            for (int i = 0; i < 32; ++i) bv[i] = dpp_xor1(hh[18 + i]);
            // Shift window by 32 (descending; read range 49..0 disjoint from writes).
#pragma unroll
            for (int k = 81; k >= 32; --k) hh[k] = hh[k - 32];
#pragma unroll
            for (int i = 0; i < 32; ++i) hh[i] = bv[i];  // A's copies are dead slots
        }
        __syncthreads();
        // Coalesced flush: 128 rows x 128 cols -> out[row][128p .. 128p+127].
#pragma unroll 1
        for (int i = 0; i < 64; ++i) {
            const int idx = i * 256 + t;
            const int r = idx >> 7;
            const int cc = idx & 127;
            outb[(size_t)r * 512 + p * 128 + cc] = stage[r * STRIDE + cc];
        }
        __syncthreads();
        // Post-shift hh[32] = h(128(p+1)) -> col 0 of next phase.
        if (p < 3 && isA) stage[lrow * STRIDE] = hh[32];
    }
}

extern "C" void kernel_launch(void* const* d_in, const int* in_sizes, int n_in,
                              void* d_out, int out_size, void* d_ws, size_t ws_size,
                              hipStream_t stream) {
    const float* c = (const float*)d_in[0];
    float* out = (float*)d_out;
    // 2 lanes per row: 65536 rows * 2 / 256 = 512 blocks (2 per CU).
    cep2ir_kernel<<<512, 256, 0, stream>>>(c, out);
}

// Round 9
// 101.947 us; speedup vs baseline: 1.2086x; 1.0229x over previous
//
#include <hip/hip_runtime.h>
#include <math.h>

// CepstrumToImpulseResponse: h[0]=exp(c[0]); h[n] = (1/n) sum_{m=1..99} m*c[m]*h[n-m]
// B=65536, M=99, N=512. Output float32 [B, 512].
//
// Structure: 2 lanes per batch row (A: taps m=1..50, B: m=51..99), uniform
// 82-slot register window, all-static indexing, U=32 time unroll, DPP xor-1
// pair reduce, 1/n LDS table, LDS-staged coalesced output flush.
//
// Round-9: tap loop reversed (k = 49 -> 0). Ascending order put the
// hn-dependent FMA (k=0 reads hh[31-j], written at the end of step j) FIRST
// in a 25-deep chained accumulator -> ~110-cycle serial chain per step,
// unhidden at 2 waves/SIMD (VALUBusy 52%). Descending order issues it LAST:
// chain hn -> cndmask -> 1 FMA -> add -> dpp-add -> mul ~ 5 ops (~20 cyc).
//
// Index map (U=32): frame A: hh[i]=h(n0+31-i); B: hh[i]=h(n0-19-i).
//   step j, tap k: read s = k+32-j (in [1,81]); fresh h(n0+j) -> slot 31-j (A).
//   group end: bv[i] = xor1(hh[18+i]) pre-shift; shift hh[81..32] <- hh[49..0];
//   hh[0..31] <- bv. Seed h(0) at slot 32. Phase carry: post-shift hh[32].

#define NROWS   128   // rows per 256-thread block (2 lanes per row)
#define STRIDE  129   // LDS row stride in floats; col 128 = dump slot

__device__ __forceinline__ float dpp_xor1(float x) {   // quad_perm [1,0,3,2]
    return __int_as_float(__builtin_amdgcn_mov_dpp(__float_as_int(x), 0xB1, 0xF, 0xF, false));
}

__global__ __launch_bounds__(256, 2)
void cep2ir_kernel(const float* __restrict__ c, float* __restrict__ out) {
    __shared__ float stage[NROWS * STRIDE];
    __shared__ float4 rn4[128];              // ((float*)rn4)[i] = 1/(i+1), i=0..510
    const int t = threadIdx.x;
    const int lrow = t >> 1;                 // local row 0..127
    const bool isA = (t & 1) == 0;
    const int rowbase = blockIdx.x * NROWS;
    const float* cb = c + (size_t)(rowbase + lrow) * 100;
    float* outb = out + (size_t)rowbase * 512;

    // 1/n table: each thread fills entries t and t+256.
    {
        float* rt = reinterpret_cast<float*>(rn4);
        rt[t]       = __builtin_amdgcn_rcpf((float)(t + 1));
        rt[t + 256] = __builtin_amdgcn_rcpf((float)(t + 257));
    }

    // Load 13 float4 = 52 floats: A covers c[0..51], B covers c[48..99].
    float e[52];
    {
        const float4* c4 = reinterpret_cast<const float4*>(cb);
        const int f4b = isA ? 0 : 12;
#pragma unroll
        for (int i = 0; i < 13; ++i) {
            const float4 v = c4[f4b + i];
            e[4 * i + 0] = v.x; e[4 * i + 1] = v.y;
            e[4 * i + 2] = v.z; e[4 * i + 3] = v.w;
        }
    }
    // Weights: A: w[k]=c[k+1]*(k+1); B: w[k]=c[51+k]*(51+k), k=0..48; w[49]=0 on B.
    float w[50];
#pragma unroll
    for (int k = 0; k < 49; ++k)
        w[k] = (isA ? e[k + 1] : e[k + 3]) * (isA ? (float)(k + 1) : (float)(k + 51));
    w[49] = isA ? e[50] * 50.0f : 0.0f;

    const float h0 = expf(e[0]);  // meaningful on lane A

    float hh[82];
#pragma unroll
    for (int k = 0; k < 82; ++k) hh[k] = 0.0f;
    hh[32] = isA ? h0 : 0.0f;     // h(0) in A frame (n0=1)

    if (isA) stage[lrow * STRIDE] = h0;   // col 0 of phase 0
    __syncthreads();                      // rn table + h0 staged

#pragma unroll 1
    for (int p = 0; p < 4; ++p) {
#pragma unroll 1
        for (int gg = 0; gg < 4; ++gg) {
            // 1/n for the 32 steps: broadcast ds_read_b128 x8, off the chain.
            float4 r4[8];
            {
                const float4* rp = &rn4[8 * (4 * p + gg)];
#pragma unroll
                for (int i = 0; i < 8; ++i) r4[i] = rp[i];
            }
#pragma unroll
            for (int j = 0; j < 32; ++j) {
                float a0 = 0.f, a1 = 0.f;
                // Descending k: the hn-dependent tap (k=0, slot 31-(j-1)) is LAST.
#pragma unroll
                for (int k = 49; k >= 0; --k) {
                    if ((k & 1) == 0) a0 = __builtin_fmaf(w[k], hh[k + 32 - j], a0);
                    else              a1 = __builtin_fmaf(w[k], hh[k + 32 - j], a1);
                }
                float s = a0 + a1;
                s += dpp_xor1(s);                       // pair reduce (fusable DPP)
                const float rn = (j & 2) ? ((j & 1) ? r4[j >> 2].w : r4[j >> 2].z)
                                         : ((j & 1) ? r4[j >> 2].y : r4[j >> 2].x);
                const float hn = s * rn;
                hh[31 - j] = isA ? hn : hh[31 - j];     // only A's frame takes fresh h
            }
            // Batched stores: A's hh[31..0] = h(n0..n0+31) -> cols 1+32gg .. 32+32gg.
            // (gg==3, j==31 lands in dump col 128; n=128(p+1) re-emerges as carry.)
            if (isA) {
                float* sc = &stage[lrow * STRIDE + 1 + 32 * gg];
#pragma unroll
                for (int j = 0; j < 32; ++j) sc[j] = hh[31 - j];
            }
            // Boundary (pre-shift reads): B's next slots 0..31 = A's h(n0+13..n0-18).
            float bv[32];
#pragma unroll
            for (int i = 0; i < 32; ++i) bv[i] = dpp_xor1(hh[18 + i]);
            // Shift window by 32 (descending; read range 49..0 disjoint from writes).
#pragma unroll
            for (int k = 81; k >= 32; --k) hh[k] = hh[k - 32];
#pragma unroll
            for (int i = 0; i < 32; ++i) hh[i] = bv[i];  // A's copies are dead slots
        }
        __syncthreads();
        // Coalesced flush: 128 rows x 128 cols -> out[row][128p .. 128p+127].
#pragma unroll 1
        for (int i = 0; i < 64; ++i) {
            const int idx = i * 256 + t;
            const int r = idx >> 7;
            const int cc = idx & 127;
            outb[(size_t)r * 512 + p * 128 + cc] = stage[r * STRIDE + cc];
        }
        __syncthreads();
        // Post-shift hh[32] = h(128(p+1)) -> col 0 of next phase.
        if (p < 3 && isA) stage[lrow * STRIDE] = hh[32];
    }
}

extern "C" void kernel_launch(void* const* d_in, const int* in_sizes, int n_in,
                              void* d_out, int out_size, void* d_ws, size_t ws_size,
                              hipStream_t stream) {
    const float* c = (const float*)d_in[0];
    float* out = (float*)d_out;
    // 2 lanes per row: 65536 rows * 2 / 256 = 512 blocks (2 per CU).
    cep2ir_kernel<<<512, 256, 0, stream>>>(c, out);
}

// Round 10
// 101.087 us; speedup vs baseline: 1.2188x; 1.0085x over previous
//
#include <hip/hip_runtime.h>
#include <math.h>

// CepstrumToImpulseResponse: h[0]=exp(c[0]); h[n] = (1/n) sum_{m=1..99} m*c[m]*h[n-m]
// B=65536, M=99, N=512. Output float32 [B, 512].
//
// Structure: 2 lanes per batch row (A: taps m=1..50, B: m=51..99), uniform
// 82-slot register window, all-static indexing, U=32 time unroll, DPP xor-1
// pair reduce, 1/n LDS table, reversed tap loop (hn-dependent FMA last).
//
// Round-10: overlap output flush with compute. 8 phases x 64 cols, double-
// buffered LDS stage (2 x 128 x 66 floats): phase p computes into buf[p&1]
// while the flush of buf[(p-1)&1] (float2 LDS reads + coalesced
// global_store_dwordx2) is interleaved into the compute groups. R9's flush
// was serial between barriers: ~21 us of HBM store time + scalar issue with
// zero overlap (vmcnt(0) drained at each barrier). Compute math identical
// to R9 (groups advance n0 by 32 globally; only store plumbing changed).
//
// Index map (U=32): frame A: hh[i]=h(n0+31-i); B: hh[i]=h(n0-19-i).
//   step j, tap k: read s = k+32-j in [1,81]; fresh h(n0+j) -> slot 31-j (A).
//   group end: bv[i]=xor1(hh[18+i]) pre-shift; shift hh[81..32]<-hh[49..0];
//   hh[0..31]<-bv. Seed h(0) at slot 32. Post-shift hh[32] = h(32*(gidx+1)).
// Stage stride 66: 264B rows (8B-aligned float2) and bank stride 2 -> worst
// 2-way LDS conflicts (free). Col 64 = dump slot for the carry store.

#define NROWS   128
#define STRIDE  66    // 64 data cols + dump col 64 + pad

__device__ __forceinline__ float dpp_xor1(float x) {   // quad_perm [1,0,3,2]
    return __int_as_float(__builtin_amdgcn_mov_dpp(__float_as_int(x), 0xB1, 0xF, 0xF, false));
}

__global__ __launch_bounds__(256, 2)
void cep2ir_kernel(const float* __restrict__ c, float* __restrict__ out) {
    __shared__ float buf[2][NROWS * STRIDE];
    __shared__ float4 rn4[128];              // ((float*)rn4)[i] = 1/(i+1), i=0..510
    const int t = threadIdx.x;
    const int lrow = t >> 1;                 // local row 0..127
    const bool isA = (t & 1) == 0;
    const int rowbase = blockIdx.x * NROWS;
    const float* cb = c + (size_t)(rowbase + lrow) * 100;
    float* outb = out + (size_t)rowbase * 512;

    // 1/n table: each thread fills entries t and t+256.
    {
        float* rt = reinterpret_cast<float*>(rn4);
        rt[t]       = __builtin_amdgcn_rcpf((float)(t + 1));
        rt[t + 256] = __builtin_amdgcn_rcpf((float)(t + 257));
    }

    // Load 13 float4 = 52 floats: A covers c[0..51], B covers c[48..99].
    float e[52];
    {
        const float4* c4 = reinterpret_cast<const float4*>(cb);
        const int f4b = isA ? 0 : 12;
#pragma unroll
        for (int i = 0; i < 13; ++i) {
            const float4 v = c4[f4b + i];
            e[4 * i + 0] = v.x; e[4 * i + 1] = v.y;
            e[4 * i + 2] = v.z; e[4 * i + 3] = v.w;
        }
    }
    // Weights: A: w[k]=c[k+1]*(k+1); B: w[k]=c[51+k]*(51+k), k=0..48; w[49]=0 on B.
    float w[50];
#pragma unroll
    for (int k = 0; k < 49; ++k)
        w[k] = (isA ? e[k + 1] : e[k + 3]) * (isA ? (float)(k + 1) : (float)(k + 51));
    w[49] = isA ? e[50] * 50.0f : 0.0f;

    const float h0 = expf(e[0]);  // meaningful on lane A

    float hh[82];
#pragma unroll
    for (int k = 0; k < 82; ++k) hh[k] = 0.0f;
    hh[32] = isA ? h0 : 0.0f;     // h(0) in A frame (n0=1)

    if (isA) buf[0][lrow * STRIDE] = h0;   // col 0 of phase 0
    __syncthreads();                       // rn table + h0 staged

#pragma unroll 1
    for (int p = 0; p < 8; ++p) {
        // Carry h(64p) (post-shift hh[32] from phase p-1) -> col 0 of this buffer.
        if (p > 0 && isA) buf[p & 1][lrow * STRIDE] = hh[32];
#pragma unroll 1
        for (int g = 0; g < 2; ++g) {
            const int gidx = 2 * p + g;
            // 1/n for the 32 steps: broadcast ds_read_b128 x8, off the chain.
            float4 r4[8];
            {
                const float4* rp = &rn4[8 * gidx];
#pragma unroll
                for (int i = 0; i < 8; ++i) r4[i] = rp[i];
            }
            // Interleaved flush chunk: 8 float2 rows-segments of phase p-1's buffer.
            if (p > 0) {
                const float* fb = buf[(p & 1) ^ 1];
                const int colbase = 64 * (p - 1);
#pragma unroll
                for (int i = 0; i < 8; ++i) {
                    const int idx = (8 * g + i) * 256 + t;
                    const int r = idx >> 5;          // 0..127
                    const int c2 = idx & 31;         // float2 index within 64 cols
                    const float2 v = *reinterpret_cast<const float2*>(&fb[r * STRIDE + 2 * c2]);
                    *reinterpret_cast<float2*>(&outb[(size_t)r * 512 + colbase + 2 * c2]) = v;
                }
            }
#pragma unroll
            for (int j = 0; j < 32; ++j) {
                float a0 = 0.f, a1 = 0.f;
                // Descending k: the hn-dependent tap (k=0) issues LAST.
#pragma unroll
                for (int k = 49; k >= 0; --k) {
                    if ((k & 1) == 0) a0 = __builtin_fmaf(w[k], hh[k + 32 - j], a0);
                    else              a1 = __builtin_fmaf(w[k], hh[k + 32 - j], a1);
                }
                float s = a0 + a1;
                s += dpp_xor1(s);                       // pair reduce
                const float rn = (j & 2) ? ((j & 1) ? r4[j >> 2].w : r4[j >> 2].z)
                                         : ((j & 1) ? r4[j >> 2].y : r4[j >> 2].x);
                const float hn = s * rn;
                hh[31 - j] = isA ? hn : hh[31 - j];     // only A's frame takes fresh h
            }
            // Batched stores: A's hh[31..0] = h(n0..n0+31) -> cols 1+32g..32+32g.
            // (g==1, j==31 lands in dump col 64; that value re-emerges as carry.)
            if (isA) {
                float* sc = &buf[p & 1][lrow * STRIDE + 1 + 32 * g];
#pragma unroll
                for (int j = 0; j < 32; ++j) sc[j] = hh[31 - j];
            }
            // Boundary (pre-shift reads): B's next slots 0..31 = A's h(n0+13..n0-18).
            float bv[32];
#pragma unroll
            for (int i = 0; i < 32; ++i) bv[i] = dpp_xor1(hh[18 + i]);
            // Shift window by 32 (descending; read range 49..0 disjoint from writes).
#pragma unroll
            for (int k = 81; k >= 32; --k) hh[k] = hh[k - 32];
#pragma unroll
            for (int i = 0; i < 32; ++i) hh[i] = bv[i];  // A's copies are dead slots
        }
        __syncthreads();   // compute writes visible to next phase's flush readers
    }
    // Tail flush: phase 7's buffer (buf[1]) -> out cols 448..511.
#pragma unroll 1
    for (int i = 0; i < 16; ++i) {
        const int idx = i * 256 + t;
        const int r = idx >> 5;
        const int c2 = idx & 31;
        const float2 v = *reinterpret_cast<const float2*>(&buf[1][r * STRIDE + 2 * c2]);
        *reinterpret_cast<float2*>(&outb[(size_t)r * 512 + 448 + 2 * c2]) = v;
    }
}

extern "C" void kernel_launch(void* const* d_in, const int* in_sizes, int n_in,
                              void* d_out, int out_size, void* d_ws, size_t ws_size,
                              hipStream_t stream) {
    const float* c = (const float*)d_in[0];
    float* out = (float*)d_out;
    // 2 lanes per row: 65536 rows * 2 / 256 = 512 blocks (2 per CU).
    cep2ir_kernel<<<512, 256, 0, stream>>>(c, out);
}